// Round 6
// baseline (651.341 us; speedup 1.0000x reference)
//
#include <hip/hip_runtime.h>
#include <stdint.h>
#include <math.h>

#define B_ 8
#define N_ 4096
#define DIM_ 1024
#define H_ 16
#define M_ (B_*N_)   // 32768

typedef unsigned short u16;
typedef __attribute__((ext_vector_type(8))) short bf16x8;
typedef __attribute__((ext_vector_type(4))) float f32x4;

// ---------------------------------------------------------------- bf16 utils
__device__ __forceinline__ u16 f2bf(float f) {          // RNE (prep / exactness)
    union { float f; uint32_t u; } c; c.f = f;
    uint32_t r = (c.u + 0x7fffu + ((c.u >> 16) & 1u)) >> 16;
    return (u16)r;
}
__device__ __forceinline__ u16 f2bf_fast(float f) {     // round-half-up, 2 insts
    union { float f; uint32_t u; } c; c.f = f;
    return (u16)((c.u + 0x8000u) >> 16);
}
__device__ __forceinline__ float bf2f(u16 u) {
    union { uint32_t u; float f; } c; c.u = ((uint32_t)u) << 16;
    return c.f;
}
__device__ __forceinline__ void gload_lds16(const void* g, void* l) {
    __builtin_amdgcn_global_load_lds(
        (const __attribute__((address_space(1))) uint32_t*)g,
        (__attribute__((address_space(3))) uint32_t*)l, 16, 0, 0);
}

// ============================================================================
// MFMA GEMM, 2-term split (A-high x (B-high + B-low)):
//   C[r,j] = sum_k bf16(Asrc_scaled)[r,k] * (Bh+Bl)[j,k]   (NT GEMM)
// A is REG-STAGED from fp32 (global->reg->cvt->ds_write), fusing:
//   MODE 1 (GEMM1): scale = 1 (plain cvt of x); epilogue writes w fp32 +
//                   fused column sum-of-squares -> norm2.
//   MODE 0 (GEMM2): scale = -Pi[r,h]*attn[b,c], attn = S/(S+T) built once
//                   per block into a 4KB LDS table; epilogue adds bias.
// Tile 256x128, BK=32, 8 waves (4Mx2N), each wave 64x64 = 4x4 16x16 frags.
// A-LDS XOR-swizzled (elem offset ^= (row&3)<<3): 8-way ds_read_b128
// conflict -> free 2-way. B stays global_load_lds (linear, unswizzlable).
// ============================================================================
template<int MODE>
__global__ __launch_bounds__(512)
void gemm_mfma(const float* __restrict__ Asrc,
               const u16* __restrict__ Bh, const u16* __restrict__ Bl,
               const float* __restrict__ bias, float* __restrict__ Cf,
               float* __restrict__ norm2,
               const float* __restrict__ Pi, const float* __restrict__ Sg,
               const float* __restrict__ Tg)
{
    __shared__ u16 sA[256*32];                 // 16 KB, XOR-swizzled
    __shared__ u16 sBh[128*32], sBl[128*32];   // 8 KB each, linear
    __shared__ float atn[DIM_];                // 4 KB (MODE 0)
    __shared__ float cs[128];                  // (MODE 1)
    const int tid  = threadIdx.x;    // 0..511
    const int wid  = tid >> 6;       // 0..7
    const int lane = tid & 63;
    // bijective chunked XCD swizzle: 1024 blocks -> 128 contiguous per XCD;
    // each XCD owns 16 full row-slabs (all col-blocks) -> A re-reads L2-local
    const int bid = blockIdx.x;
    const int lin = (bid & 7) * 128 + (bid >> 3);
    const int bx = lin & 7;          // col block 0..7   (128 cols)
    const int by = lin >> 3;         // row block 0..127 (256 rows)
    const int wm = wid >> 1, wn = wid & 1;   // wave grid 4x2
    const int fr = lane & 15;
    const int kb = (lane >> 4) * 8;  // k-element offset of this lane's frag

    const int arow = by * 256;
    const int brow = bx * 128;
    const int bb   = arow >> 12;     // batch (256 | 4096 -> uniform)

    if (MODE == 0) {
        // attn table for this block's batch: attn[c] = S/(S + T)
        for (int c = tid; c < DIM_; c += 512) {
            const float Sv = Sg[bb * H_ + (c >> 6)] + 1e-8f;
            atn[c] = Sv / (Sv + Tg[bb * DIM_ + c]);
        }
        __syncthreads();
    }

    f32x4 acc[4][4] = {};

    const int ar = (tid >> 3);       // A row within 64-row group
    const int c4 = (tid & 7) * 4;    // A k-offset (4 consecutive, same head)
    const int sw = ((ar & 3) << 3);  // A-LDS XOR swizzle (rows repeat mod 4)

    for (int k0 = 0; k0 < DIM_; k0 += 32) {
        // ---- B: global_load_lds, linear [128][32] bf16 each
        {
            const int row  = tid >> 2;              // 0..127
            const int ce   = (tid & 3) * 8;
            const int soff = wid * 512;             // wave-uniform elem offset
            gload_lds16(Bh + (size_t)(brow + row) * DIM_ + k0 + ce, sBh + soff);
            gload_lds16(Bl + (size_t)(brow + row) * DIM_ + k0 + ce, sBl + soff);
        }
        // ---- A: reg-stage fp32 -> (scaled) bf16
        ushort4 av[4];
        #pragma unroll
        for (int i = 0; i < 4; ++i) {
            const int r = i * 64 + ar;              // 0..255
            const float4 v = *(const float4*)(Asrc + (size_t)(arow + r) * DIM_ + k0 + c4);
            float s0, s1, s2, s3;
            if (MODE == 0) {
                const int c = k0 + c4;
                const float p = -Pi[(size_t)(arow + r) * H_ + (c >> 6)];
                const float4 a4 = *(const float4*)&atn[c];
                s0 = v.x * p * a4.x; s1 = v.y * p * a4.y;
                s2 = v.z * p * a4.z; s3 = v.w * p * a4.w;
            } else { s0 = v.x; s1 = v.y; s2 = v.z; s3 = v.w; }
            av[i].x = f2bf_fast(s0); av[i].y = f2bf_fast(s1);
            av[i].z = f2bf_fast(s2); av[i].w = f2bf_fast(s3);
        }
        #pragma unroll
        for (int i = 0; i < 4; ++i) {
            const int r = i * 64 + ar;
            *(ushort4*)(sA + r * 32 + (c4 ^ sw)) = av[i];
        }
        __syncthreads();

        bf16x8 a_[4], bh_[4], bl_[4];
        #pragma unroll
        for (int m = 0; m < 4; ++m) {
            const int r = wm * 64 + m * 16 + fr;
            a_[m] = *(const bf16x8*)(sA + r * 32 + (kb ^ ((r & 3) << 3)));
        }
        #pragma unroll
        for (int n = 0; n < 4; ++n) {
            const int c = wn * 64 + n * 16 + fr;
            bh_[n] = *(const bf16x8*)(sBh + c * 32 + kb);
            bl_[n] = *(const bf16x8*)(sBl + c * 32 + kb);
        }
        #pragma unroll
        for (int m = 0; m < 4; ++m)
            #pragma unroll
            for (int n = 0; n < 4; ++n)
                acc[m][n] = __builtin_amdgcn_mfma_f32_16x16x32_bf16(a_[m], bh_[n], acc[m][n], 0, 0, 0);
        #pragma unroll
        for (int m = 0; m < 4; ++m)
            #pragma unroll
            for (int n = 0; n < 4; ++n)
                acc[m][n] = __builtin_amdgcn_mfma_f32_16x16x32_bf16(a_[m], bl_[n], acc[m][n], 0, 0, 0);
        __syncthreads();
    }

    if (MODE == 1) {
        if (tid < 128) cs[tid] = 0.f;
        __syncthreads();
    }

    // epilogue: C/D layout col=lane&15, row=(lane>>4)*4+j  [m89]
    const int fq = lane >> 4;
    float csum[4] = {0.f, 0.f, 0.f, 0.f};
    #pragma unroll
    for (int m = 0; m < 4; ++m)
        #pragma unroll
        for (int n = 0; n < 4; ++n) {
            const int col  = bx * 128 + wn * 64 + n * 16 + fr;
            const int row0 = arow + wm * 64 + m * 16 + fq * 4;
            const float bv = (MODE == 0) ? bias[col] : 0.f;
            #pragma unroll
            for (int j = 0; j < 4; ++j) {
                const float v = acc[m][n][j];
                Cf[(size_t)(row0 + j) * DIM_ + col] = v + bv;
                if (MODE == 1) csum[n] = fmaf(v, v, csum[n]);
            }
        }

    if (MODE == 1) {
        #pragma unroll
        for (int n = 0; n < 4; ++n)
            atomicAdd(&cs[wn * 64 + n * 16 + fr], csum[n]);
        __syncthreads();
        if (tid < 128) atomicAdd(&norm2[bb * DIM_ + bx * 128 + tid], cs[tid]);
    }
}

// ============================================================================
// prep: split Wqkv/Wout fp32 -> (hi,lo) bf16 pairs; zero norm2/S/T stats.
// 1024 blocks x 256 threads; i indexes float4 (DD/4 = 262144 = grid exactly).
// ============================================================================
__global__ __launch_bounds__(256)
void prep(const float* __restrict__ Wqkv, const float* __restrict__ Wout,
          u16* __restrict__ qh, u16* __restrict__ ql,
          u16* __restrict__ oh, u16* __restrict__ ol,
          float* __restrict__ stats)
{
    const int i = blockIdx.x * 256 + threadIdx.x;
    {
        const float4 v = ((const float4*)Wqkv)[i];
        ushort4 h, l;
        h.x = f2bf(v.x); l.x = f2bf(v.x - bf2f(h.x));
        h.y = f2bf(v.y); l.y = f2bf(v.y - bf2f(h.y));
        h.z = f2bf(v.z); l.z = f2bf(v.z - bf2f(h.z));
        h.w = f2bf(v.w); l.w = f2bf(v.w - bf2f(h.w));
        ((ushort4*)qh)[i] = h; ((ushort4*)ql)[i] = l;
    }
    {
        const float4 v = ((const float4*)Wout)[i];
        ushort4 h, l;
        h.x = f2bf(v.x); l.x = f2bf(v.x - bf2f(h.x));
        h.y = f2bf(v.y); l.y = f2bf(v.y - bf2f(h.y));
        h.z = f2bf(v.z); l.z = f2bf(v.z - bf2f(h.z));
        h.w = f2bf(v.w); l.w = f2bf(v.w - bf2f(h.w));
        ((ushort4*)oh)[i] = h; ((ushort4*)ol)[i] = l;
    }
    if (i < 8192 + 128 + 8192) stats[i] = 0.f;
}

// ============================================================================
// Fused middle stage: per row r=(b,n):
//   logits[h] = temp[h]*sum_{c in head h} w[r,c]^2 / max(norm2[b,c],eps^2)
//   Pi = softmax over 16 heads; S[b,h] += sum_n Pi; T[b,c] += sum_n Pi*w^2.
// Block = 4 waves x 16 rows = 64 rows; per-wave LDS T slabs, one atomic
// flush per block.
// ============================================================================
__global__ __launch_bounds__(256)
void softmax_T(const float* __restrict__ w, const float* __restrict__ norm2,
               const float* __restrict__ temp, float* __restrict__ Pi,
               float* __restrict__ S, float* __restrict__ T)
{
    __shared__ float Tacc[4][1024];   // 16 KB, per-wave slabs
    __shared__ float sS[H_];
    const int tid  = threadIdx.x;
    const int wv   = tid >> 6;
    const int lane = tid & 63;
    const int g    = lane >> 4;       // 16-lane group -> head sub-index

    #pragma unroll
    for (int z = 0; z < 4; ++z)
        ((float4*)&Tacc[0][0])[z * 256 + tid] = float4{0.f, 0.f, 0.f, 0.f};
    if (tid < H_) sS[tid] = 0.f;
    __syncthreads();

    const int b = (blockIdx.x * 64) >> 12;   // 64 | 4096 -> uniform per block
    float tl[4];
    float4 iv[4];
    #pragma unroll
    for (int rep = 0; rep < 4; ++rep) {
        tl[rep] = temp[rep * 4 + g];
        const int c = rep * 256 + lane * 4;
        const float4 nv = *(const float4*)(norm2 + (size_t)b * DIM_ + c);
        iv[rep].x = 1.0f / fmaxf(nv.x, 1e-24f);
        iv[rep].y = 1.0f / fmaxf(nv.y, 1e-24f);
        iv[rep].z = 1.0f / fmaxf(nv.z, 1e-24f);
        iv[rep].w = 1.0f / fmaxf(nv.w, 1e-24f);
    }

    float sSl[4] = {0.f, 0.f, 0.f, 0.f};

    for (int q = 0; q < 16; ++q) {
        const int r = blockIdx.x * 64 + wv * 16 + q;
        float4 wsq[4];
        float  l[4];
        #pragma unroll
        for (int rep = 0; rep < 4; ++rep) {
            const int c = rep * 256 + lane * 4;          // head = rep*4 + g
            const float4 w4 = *(const float4*)(w + (size_t)r * DIM_ + c);
            wsq[rep].x = w4.x * w4.x; wsq[rep].y = w4.y * w4.y;
            wsq[rep].z = w4.z * w4.z; wsq[rep].w = w4.w * w4.w;
            l[rep] = wsq[rep].x * iv[rep].x + wsq[rep].y * iv[rep].y
                   + wsq[rep].z * iv[rep].z + wsq[rep].w * iv[rep].w;
        }
        #pragma unroll
        for (int off = 1; off < 16; off <<= 1)
            #pragma unroll
            for (int rep = 0; rep < 4; ++rep) l[rep] += __shfl_xor(l[rep], off, 64);
        #pragma unroll
        for (int rep = 0; rep < 4; ++rep) l[rep] *= tl[rep];

        float m = fmaxf(fmaxf(l[0], l[1]), fmaxf(l[2], l[3]));
        m = fmaxf(m, __shfl_xor(m, 16, 64));
        m = fmaxf(m, __shfl_xor(m, 32, 64));
        float e[4], s = 0.f;
        #pragma unroll
        for (int rep = 0; rep < 4; ++rep) { e[rep] = expf(l[rep] - m); s += e[rep]; }
        s += __shfl_xor(s, 16, 64);
        s += __shfl_xor(s, 32, 64);
        const float inv_s = 1.0f / s;

        float pi[4];
        #pragma unroll
        for (int rep = 0; rep < 4; ++rep) pi[rep] = e[rep] * inv_s;

        #pragma unroll
        for (int rep = 0; rep < 4; ++rep) {
            const int c = rep * 256 + lane * 4;
            float4* t = (float4*)&Tacc[wv][c];
            float4 tv = *t;
            tv.x = fmaf(pi[rep], wsq[rep].x, tv.x);
            tv.y = fmaf(pi[rep], wsq[rep].y, tv.y);
            tv.z = fmaf(pi[rep], wsq[rep].z, tv.z);
            tv.w = fmaf(pi[rep], wsq[rep].w, tv.w);
            *t = tv;
        }

        if ((lane & 15) == 0) {
            #pragma unroll
            for (int rep = 0; rep < 4; ++rep) {
                Pi[(size_t)r * H_ + rep * 4 + g] = pi[rep];
                sSl[rep] += pi[rep];
            }
        }
    }

    if ((lane & 15) == 0) {
        #pragma unroll
        for (int rep = 0; rep < 4; ++rep) atomicAdd(&sS[rep * 4 + g], sSl[rep]);
    }
    __syncthreads();
    if (tid < H_) atomicAdd(&S[b * H_ + tid], sS[tid]);
    #pragma unroll
    for (int z = 0; z < 4; ++z) {
        const int c = z * 256 + tid;
        const float t = Tacc[0][c] + Tacc[1][c] + Tacc[2][c] + Tacc[3][c];
        atomicAdd(&T[b * DIM_ + c], t);
    }
}

// ============================================================================
// ===================== fp32 VALU fallback path (round-0) ====================
// ============================================================================
template<bool FUSE>
__global__ __launch_bounds__(256, 4)
void gemm128(const float* __restrict__ A, const float* __restrict__ Bw,
             const float* __restrict__ bias, float* __restrict__ C,
             const float* __restrict__ Pi, const float* __restrict__ attn)
{
    __shared__ float As[16][128];
    __shared__ float Bs[16][128];
    const int tid  = threadIdx.x;
    const int bx   = blockIdx.x;
    const int by   = blockIdx.y;
    const int lrow = tid >> 2;
    const int lk   = (tid & 3) << 2;
    const int tx   = tid & 15;
    const int ty   = tid >> 4;
    const size_t K = DIM_;
    const float* Ap = A  + (size_t)(by * 128 + lrow) * K + lk;
    const float* Bp = Bw + (size_t)(bx * 128 + lrow) * K + lk;

    float acc[8][8];
    #pragma unroll
    for (int i = 0; i < 8; ++i)
        #pragma unroll
        for (int j = 0; j < 8; ++j) acc[i][j] = 0.f;

    for (int k0 = 0; k0 < DIM_; k0 += 16) {
        float4 a0 = *(const float4*)(Ap + k0);
        float4 a1 = *(const float4*)(Ap + k0 + (size_t)64 * K);
        float4 b0 = *(const float4*)(Bp + k0);
        float4 b1 = *(const float4*)(Bp + k0 + (size_t)64 * K);
        if (FUSE) {
            const int r0 = by * 128 + lrow;
            const int c  = k0 + lk;
            const int b  = r0 >> 12;
            const float4 at = *(const float4*)(attn + b * DIM_ + c);
            const float p0 = -Pi[(size_t)r0 * H_ + (c >> 6)];
            const float p1 = -Pi[(size_t)(r0 + 64) * H_ + (c >> 6)];
            a0.x *= p0 * at.x; a0.y *= p0 * at.y; a0.z *= p0 * at.z; a0.w *= p0 * at.w;
            a1.x *= p1 * at.x; a1.y *= p1 * at.y; a1.z *= p1 * at.z; a1.w *= p1 * at.w;
        }
        __syncthreads();
        As[lk + 0][lrow]      = a0.x; As[lk + 1][lrow]      = a0.y;
        As[lk + 2][lrow]      = a0.z; As[lk + 3][lrow]      = a0.w;
        As[lk + 0][lrow + 64] = a1.x; As[lk + 1][lrow + 64] = a1.y;
        As[lk + 2][lrow + 64] = a1.z; As[lk + 3][lrow + 64] = a1.w;
        Bs[lk + 0][lrow]      = b0.x; Bs[lk + 1][lrow]      = b0.y;
        Bs[lk + 2][lrow]      = b0.z; Bs[lk + 3][lrow]      = b0.w;
        Bs[lk + 0][lrow + 64] = b1.x; Bs[lk + 1][lrow + 64] = b1.y;
        Bs[lk + 2][lrow + 64] = b1.z; Bs[lk + 3][lrow + 64] = b1.w;
        __syncthreads();
        #pragma unroll
        for (int kk = 0; kk < 16; ++kk) {
            const float4 av0 = *(const float4*)&As[kk][ty * 4];
            const float4 av1 = *(const float4*)&As[kk][ty * 4 + 64];
            const float4 bv0 = *(const float4*)&Bs[kk][tx * 4];
            const float4 bv1 = *(const float4*)&Bs[kk][tx * 4 + 64];
            const float a[8] = {av0.x, av0.y, av0.z, av0.w, av1.x, av1.y, av1.z, av1.w};
            const float b[8] = {bv0.x, bv0.y, bv0.z, bv0.w, bv1.x, bv1.y, bv1.z, bv1.w};
            #pragma unroll
            for (int i = 0; i < 8; ++i)
                #pragma unroll
                for (int j = 0; j < 8; ++j)
                    acc[i][j] = fmaf(a[i], b[j], acc[i][j]);
        }
    }
    #pragma unroll
    for (int i = 0; i < 8; ++i) {
        const int r = by * 128 + ((i < 4) ? (ty * 4 + i) : (64 + ty * 4 + (i - 4)));
        #pragma unroll
        for (int jb = 0; jb < 2; ++jb) {
            const int c0 = bx * 128 + (jb ? (64 + tx * 4) : (tx * 4));
            float4 v;
            v.x = acc[i][jb * 4 + 0]; v.y = acc[i][jb * 4 + 1];
            v.z = acc[i][jb * 4 + 2]; v.w = acc[i][jb * 4 + 3];
            if (bias) {
                const float4 bv = *(const float4*)(bias + c0);
                v.x += bv.x; v.y += bv.y; v.z += bv.z; v.w += bv.w;
            }
            *(float4*)(C + (size_t)r * DIM_ + c0) = v;
        }
    }
}

__global__ __launch_bounds__(256)
void colsum_sq_f32(const float* __restrict__ w, float* __restrict__ norm2)
{
    const int c  = blockIdx.x * 256 + threadIdx.x;
    const int b  = blockIdx.z;
    const int n0 = blockIdx.y * (N_ / 16);
    const float* p = w + (size_t)(b * N_ + n0) * DIM_ + c;
    float s = 0.f;
    for (int n = 0; n < N_ / 16; ++n) {
        const float v = p[(size_t)n * DIM_];
        s = fmaf(v, v, s);
    }
    atomicAdd(&norm2[b * DIM_ + c], s);
}

__global__ void finalize_inv(float* __restrict__ norm2)
{
    const int i = blockIdx.x * 256 + threadIdx.x;   // 8192
    norm2[i] = 1.0f / fmaxf(norm2[i], 1e-24f);
}

__global__ __launch_bounds__(256)
void softmax_heads_f32(const float* __restrict__ w, const float* __restrict__ inv2,
                       const float* __restrict__ temp, float* __restrict__ Pi,
                       float* __restrict__ S)
{
    __shared__ float sS[H_];
    const int tid = threadIdx.x;
    if (tid < H_) sS[tid] = 0.f;
    __syncthreads();
    const int wv   = tid >> 6;
    const int lane = tid & 63;
    const int r    = blockIdx.x * 4 + wv;
    const int b    = r >> 12;
    const int g    = lane >> 4;
    float l[4];
    #pragma unroll
    for (int rep = 0; rep < 4; ++rep) {
        const int c = rep * 256 + lane * 4;
        const float4 wv4 = *(const float4*)(w    + (size_t)r * DIM_ + c);
        const float4 iv4 = *(const float4*)(inv2 + (size_t)b * DIM_ + c);
        l[rep] = wv4.x * wv4.x * iv4.x + wv4.y * wv4.y * iv4.y
               + wv4.z * wv4.z * iv4.z + wv4.w * wv4.w * iv4.w;
    }
    #pragma unroll
    for (int off = 1; off < 16; off <<= 1)
        #pragma unroll
        for (int rep = 0; rep < 4; ++rep) l[rep] += __shfl_xor(l[rep], off, 64);
    #pragma unroll
    for (int rep = 0; rep < 4; ++rep) l[rep] *= temp[rep * 4 + g];
    float m = fmaxf(fmaxf(l[0], l[1]), fmaxf(l[2], l[3]));
    m = fmaxf(m, __shfl_xor(m, 16, 64));
    m = fmaxf(m, __shfl_xor(m, 32, 64));
    float e[4], s = 0.f;
    #pragma unroll
    for (int rep = 0; rep < 4; ++rep) { e[rep] = expf(l[rep] - m); s += e[rep]; }
    s += __shfl_xor(s, 16, 64);
    s += __shfl_xor(s, 32, 64);
    const float inv_s = 1.0f / s;
    if ((lane & 15) == 0) {
        #pragma unroll
        for (int rep = 0; rep < 4; ++rep) {
            const float pi = e[rep] * inv_s;
            Pi[(size_t)r * H_ + rep * 4 + g] = pi;
            atomicAdd(&sS[rep * 4 + g], pi);
        }
    }
    __syncthreads();
    if (tid < H_) atomicAdd(&S[b * H_ + tid], sS[tid]);
}

__global__ __launch_bounds__(256)
void colsum_T_f32(const float* __restrict__ w, const float* __restrict__ Pi,
                  float* __restrict__ T)
{
    const int c  = blockIdx.x * 256 + threadIdx.x;
    const int b  = blockIdx.z;
    const int n0 = blockIdx.y * (N_ / 16);
    const int h  = c >> 6;
    const float* p  = w  + (size_t)(b * N_ + n0) * DIM_ + c;
    const float* pp = Pi + (size_t)(b * N_ + n0) * H_ + h;
    float s = 0.f;
    for (int n = 0; n < N_ / 16; ++n) {
        const float v = p[(size_t)n * DIM_];
        s = fmaf(pp[(size_t)n * H_] * v, v, s);
    }
    atomicAdd(&T[b * DIM_ + c], s);
}

__global__ void finalize_attn(const float* __restrict__ T, const float* __restrict__ S,
                              float* __restrict__ attn)
{
    const int i = blockIdx.x * 256 + threadIdx.x;   // 8192
    const int b = i >> 10;
    const int c = i & 1023;
    const float dots = T[i] / (S[b * H_ + (c >> 6)] + 1e-8f);
    attn[i] = 1.0f / (1.0f + dots);
}

// ============================================================================
extern "C" void kernel_launch(void* const* d_in, const int* in_sizes, int n_in,
                              void* d_out, int out_size, void* d_ws, size_t ws_size,
                              hipStream_t stream)
{
    const float* x    = (const float*)d_in[0];
    const float* Wqkv = (const float*)d_in[1];
    const float* temp = (const float*)d_in[2];
    const float* Wout = (const float*)d_in[3];
    const float* bout = (const float*)d_in[4];
    float* out = (float*)d_out;

    const size_t MD = (size_t)M_ * DIM_;          // 33,554,432
    const size_t DD = (size_t)DIM_ * DIM_;        // 1,048,576
    const size_t NEED_MFMA = MD * 4            // w fp32
                           + 4 * DD * 2        // qh, ql, oh, ol
                           + (size_t)M_ * H_ * 4
                           + (size_t)(8192 + 128 + 8192) * 4 + 4096;

    if (ws_size >= NEED_MFMA) {
        // ---------------- fused 2-term split-bf16 MFMA path ----------------
        uint8_t* p = (uint8_t*)d_ws;
        float* w = (float*)p; p += MD * 4;
        u16* qh = (u16*)p; p += DD * 2;
        u16* ql = (u16*)p; p += DD * 2;
        u16* oh = (u16*)p; p += DD * 2;
        u16* ol = (u16*)p; p += DD * 2;
        float* Pi    = (float*)p; p += (size_t)M_ * H_ * 4;
        float* norm2 = (float*)p; p += 8192 * 4;
        float* S     = (float*)p; p += 128 * 4;
        float* T     = (float*)p;

        // 0) weight splits + stats zeroing (norm2,S,T contiguous)
        prep<<<1024, 256, 0, stream>>>(Wqkv, Wout, qh, ql, oh, ol, norm2);

        // 1) w = x @ Wqkv^T (A = fp32 x, cvt fused in staging)
        //    + fused norm2 = col sum of w^2
        gemm_mfma<1><<<1024, 512, 0, stream>>>(x, qh, ql, nullptr, w, norm2,
                                               nullptr, nullptr, nullptr);

        // 2) fused softmax(Pi) + S + T (inv2 inline from norm2)
        softmax_T<<<M_ / 64, 256, 0, stream>>>(w, norm2, temp, Pi, S, T);

        // 3) out = (-(w*Pi)*attn) @ Wout^T + bout  (scale fused in staging,
        //    attn table built per-block from T,S)
        gemm_mfma<0><<<1024, 512, 0, stream>>>(w, oh, ol, bout, out, nullptr,
                                               Pi, S, T);
    } else {
        // ---------------- fp32 VALU fallback ----------------
        float* ws    = (float*)d_ws;
        float* w     = ws;
        float* Pi    = w + MD;
        float* norm2 = Pi + (size_t)M_ * H_;
        float* S     = norm2 + 8192;
        float* T     = S + 128;
        float* attnv = T + 8192;

        hipMemsetAsync(norm2, 0, (size_t)(8192 + 128 + 8192) * 4, stream);

        gemm128<false><<<dim3(8, 256), 256, 0, stream>>>(x, Wqkv, nullptr, w, nullptr, nullptr);
        colsum_sq_f32<<<dim3(4, 16, 8), 256, 0, stream>>>(w, norm2);
        finalize_inv<<<32, 256, 0, stream>>>(norm2);
        softmax_heads_f32<<<M_ / 4, 256, 0, stream>>>(w, norm2, temp, Pi, S);
        colsum_T_f32<<<dim3(4, 16, 8), 256, 0, stream>>>(w, Pi, T);
        finalize_attn<<<32, 256, 0, stream>>>(T, S, attnv);
        gemm128<true><<<dim3(8, 256), 256, 0, stream>>>(w, Wout, bout, out, Pi, attnv);
    }
}

// Round 8
// 534.818 us; speedup vs baseline: 1.2179x; 1.2179x over previous
//
#include <hip/hip_runtime.h>
#include <stdint.h>
#include <math.h>

#define B_ 8
#define N_ 4096
#define DIM_ 1024
#define H_ 16
#define M_ (B_*N_)   // 32768

typedef unsigned short u16;
typedef __attribute__((ext_vector_type(8))) short bf16x8;
typedef __attribute__((ext_vector_type(8))) unsigned short ushort8;
typedef __attribute__((ext_vector_type(4))) float f32x4;

// ---------------------------------------------------------------- bf16 utils
__device__ __forceinline__ u16 f2bf(float f) {          // RNE
    union { float f; uint32_t u; } c; c.f = f;
    uint32_t r = (c.u + 0x7fffu + ((c.u >> 16) & 1u)) >> 16;
    return (u16)r;
}
__device__ __forceinline__ float bf2f(u16 u) {
    union { uint32_t u; float f; } c; c.u = ((uint32_t)u) << 16;
    return c.f;
}
__device__ __forceinline__ void gload_lds16(const void* g, void* l) {
    __builtin_amdgcn_global_load_lds(
        (const __attribute__((address_space(1))) uint32_t*)g,
        (__attribute__((address_space(3))) uint32_t*)l, 16, 0, 0);
}

// ============================================================================
// MFMA GEMM, 2-term split (A-high x (B-high + B-low)) — round-5 proven form.
//   C[r,j] = sum_k Ah[r,k]*(Bh+Bl)[j,k]       (NT: both K-contiguous)
// Tile 256x128, BK=32, 8 waves (4Mx2N), each wave 64x64 = 4x4 16x16 frags.
// All operands staged via global_load_lds (m151: DMA staging beats
// reg-staging at this structure — r6 measured the violation at +135us/GEMM).
// MODE 1: GEMM1 -> w fp32 + fused column sum-of-squares -> norm2
// MODE 0: GEMM2 -> out fp32 + bias
// ============================================================================
template<int MODE>
__global__ __launch_bounds__(512)
void gemm_mfma(const u16* __restrict__ Ah,
               const u16* __restrict__ Bh, const u16* __restrict__ Bl,
               const float* __restrict__ bias, float* __restrict__ Cf,
               float* __restrict__ norm2)
{
    __shared__ u16 sAh[256*32], sBh[128*32], sBl[128*32];   // 32 KB
    __shared__ float cs[128];
    const int tid  = threadIdx.x;    // 0..511
    const int wid  = tid >> 6;       // 0..7
    const int lane = tid & 63;
    // bijective chunked XCD swizzle: 1024 blocks -> 128 contiguous per XCD
    const int bid = blockIdx.x;
    const int lin = (bid & 7) * 128 + (bid >> 3);
    const int bx = lin & 7;          // col block 0..7   (128 cols)
    const int by = lin >> 3;         // row block 0..127 (256 rows)
    const int wm = wid >> 1, wn = wid & 1;   // wave grid 4x2
    const int fr = lane & 15;
    const int kb = (lane >> 4) * 8;  // k-element offset of this lane's frag

    f32x4 acc[4][4] = {};

    const int arow = by * 256;
    const int brow = bx * 128;

    for (int k0 = 0; k0 < DIM_; k0 += 32) {
        // ---- stage: A 16KB (2 rounds), Bh/Bl 8KB each (1 round), linear LDS
        #pragma unroll
        for (int i = 0; i < 2; ++i) {
            const int chunk = i * 512 + tid;        // 16B chunks
            const int row   = chunk >> 2;           // 64B per row
            const int ce    = (chunk & 3) * 8;      // element offset in row
            const int soff  = i * 4096 + wid * 512; // wave-uniform elem offset
            gload_lds16(Ah + (size_t)(arow + row) * DIM_ + k0 + ce, sAh + soff);
        }
        {
            const int row  = tid >> 2;              // 0..127
            const int ce   = (tid & 3) * 8;
            const int soff = wid * 512;
            gload_lds16(Bh + (size_t)(brow + row) * DIM_ + k0 + ce, sBh + soff);
            gload_lds16(Bl + (size_t)(brow + row) * DIM_ + k0 + ce, sBl + soff);
        }
        __syncthreads();

        bf16x8 a_[4], bh_[4], bl_[4];
        #pragma unroll
        for (int m = 0; m < 4; ++m) {
            const int r = wm * 64 + m * 16 + fr;
            a_[m] = *(const bf16x8*)(sAh + r * 32 + kb);
        }
        #pragma unroll
        for (int n = 0; n < 4; ++n) {
            const int c = wn * 64 + n * 16 + fr;
            bh_[n] = *(const bf16x8*)(sBh + c * 32 + kb);
            bl_[n] = *(const bf16x8*)(sBl + c * 32 + kb);
        }
        #pragma unroll
        for (int m = 0; m < 4; ++m)
            #pragma unroll
            for (int n = 0; n < 4; ++n)
                acc[m][n] = __builtin_amdgcn_mfma_f32_16x16x32_bf16(a_[m], bh_[n], acc[m][n], 0, 0, 0);
        #pragma unroll
        for (int m = 0; m < 4; ++m)
            #pragma unroll
            for (int n = 0; n < 4; ++n)
                acc[m][n] = __builtin_amdgcn_mfma_f32_16x16x32_bf16(a_[m], bl_[n], acc[m][n], 0, 0, 0);
        __syncthreads();
    }

    if (MODE == 1) {
        if (tid < 128) cs[tid] = 0.f;
        __syncthreads();
    }

    // epilogue: C/D layout col=lane&15, row=(lane>>4)*4+j  [m89]
    const int fq = lane >> 4;
    float csum[4] = {0.f, 0.f, 0.f, 0.f};
    #pragma unroll
    for (int m = 0; m < 4; ++m)
        #pragma unroll
        for (int n = 0; n < 4; ++n) {
            const int col  = bx * 128 + wn * 64 + n * 16 + fr;
            const int row0 = arow + wm * 64 + m * 16 + fq * 4;
            const float bv = (MODE == 0) ? bias[col] : 0.f;
            #pragma unroll
            for (int j = 0; j < 4; ++j) {
                const float v = acc[m][n][j];
                Cf[(size_t)(row0 + j) * DIM_ + col] = v + bv;
                if (MODE == 1) csum[n] = fmaf(v, v, csum[n]);
            }
        }

    if (MODE == 1) {
        #pragma unroll
        for (int n = 0; n < 4; ++n)
            atomicAdd(&cs[wn * 64 + n * 16 + fr], csum[n]);
        __syncthreads();
        const int b = arow >> 12;
        if (tid < 128) atomicAdd(&norm2[b * DIM_ + bx * 128 + tid], cs[tid]);
    }
}

// ============================================================================
// prep: split Wqkv/Wout fp32 -> (hi,lo) bf16 pairs; zero norm2/S/T stats.
// 1024 blocks x 256 threads; i indexes float4 (DD/4 = 262144 = grid exactly).
// (verified correct in r6 bench)
// ============================================================================
__global__ __launch_bounds__(256)
void prep(const float* __restrict__ Wqkv, const float* __restrict__ Wout,
          u16* __restrict__ qh, u16* __restrict__ ql,
          u16* __restrict__ oh, u16* __restrict__ ol,
          float* __restrict__ stats)
{
    const int i = blockIdx.x * 256 + threadIdx.x;
    {
        const float4 v = ((const float4*)Wqkv)[i];
        ushort4 h, l;
        h.x = f2bf(v.x); l.x = f2bf(v.x - bf2f(h.x));
        h.y = f2bf(v.y); l.y = f2bf(v.y - bf2f(h.y));
        h.z = f2bf(v.z); l.z = f2bf(v.z - bf2f(h.z));
        h.w = f2bf(v.w); l.w = f2bf(v.w - bf2f(h.w));
        ((ushort4*)qh)[i] = h; ((ushort4*)ql)[i] = l;
    }
    {
        const float4 v = ((const float4*)Wout)[i];
        ushort4 h, l;
        h.x = f2bf(v.x); l.x = f2bf(v.x - bf2f(h.x));
        h.y = f2bf(v.y); l.y = f2bf(v.y - bf2f(h.y));
        h.z = f2bf(v.z); l.z = f2bf(v.z - bf2f(h.z));
        h.w = f2bf(v.w); l.w = f2bf(v.w - bf2f(h.w));
        ((ushort4*)oh)[i] = h; ((ushort4*)ol)[i] = l;
    }
    if (i < 8192 + 128 + 8192) stats[i] = 0.f;
}

// ============================================================================
// fp32 -> bf16 (hi only), 8 elements/thread (16B stores)
// ============================================================================
__global__ __launch_bounds__(256)
void cvt_bf16(const float* __restrict__ src, u16* __restrict__ dh, int n8)
{
    const int i = blockIdx.x * 256 + threadIdx.x;
    if (i >= n8) return;
    const float4 v0 = ((const float4*)src)[i * 2];
    const float4 v1 = ((const float4*)src)[i * 2 + 1];
    ushort8 h;
    h[0] = f2bf(v0.x); h[1] = f2bf(v0.y); h[2] = f2bf(v0.z); h[3] = f2bf(v0.w);
    h[4] = f2bf(v1.x); h[5] = f2bf(v1.y); h[6] = f2bf(v1.z); h[7] = f2bf(v1.w);
    ((ushort8*)dh)[i] = h;
}

// ============================================================================
// Fused middle stage (r6-verified): per row r=(b,n):
//   logits[h] = temp[h]*sum_{c in head h} w[r,c]^2 / max(norm2[b,c],eps^2)
//   Pi = softmax over 16 heads; S[b,h] += sum_n Pi; T[b,c] += sum_n Pi*w^2.
// Block = 4 waves x 16 rows = 64 rows; per-wave LDS T slabs, one atomic
// flush per block.
// ============================================================================
__global__ __launch_bounds__(256)
void softmax_T(const float* __restrict__ w, const float* __restrict__ norm2,
               const float* __restrict__ temp, float* __restrict__ Pi,
               float* __restrict__ S, float* __restrict__ T)
{
    __shared__ float Tacc[4][1024];   // 16 KB, per-wave slabs
    __shared__ float sS[H_];
    const int tid  = threadIdx.x;
    const int wv   = tid >> 6;
    const int lane = tid & 63;
    const int g    = lane >> 4;       // 16-lane group -> head sub-index

    #pragma unroll
    for (int z = 0; z < 4; ++z)
        ((float4*)&Tacc[0][0])[z * 256 + tid] = float4{0.f, 0.f, 0.f, 0.f};
    if (tid < H_) sS[tid] = 0.f;
    __syncthreads();

    const int b = (blockIdx.x * 64) >> 12;   // 64 | 4096 -> uniform per block
    float tl[4];
    float4 iv[4];
    #pragma unroll
    for (int rep = 0; rep < 4; ++rep) {
        tl[rep] = temp[rep * 4 + g];
        const int c = rep * 256 + lane * 4;
        const float4 nv = *(const float4*)(norm2 + (size_t)b * DIM_ + c);
        iv[rep].x = 1.0f / fmaxf(nv.x, 1e-24f);
        iv[rep].y = 1.0f / fmaxf(nv.y, 1e-24f);
        iv[rep].z = 1.0f / fmaxf(nv.z, 1e-24f);
        iv[rep].w = 1.0f / fmaxf(nv.w, 1e-24f);
    }

    float sSl[4] = {0.f, 0.f, 0.f, 0.f};

    for (int q = 0; q < 16; ++q) {
        const int r = blockIdx.x * 64 + wv * 16 + q;
        float4 wsq[4];
        float  l[4];
        #pragma unroll
        for (int rep = 0; rep < 4; ++rep) {
            const int c = rep * 256 + lane * 4;          // head = rep*4 + g
            const float4 w4 = *(const float4*)(w + (size_t)r * DIM_ + c);
            wsq[rep].x = w4.x * w4.x; wsq[rep].y = w4.y * w4.y;
            wsq[rep].z = w4.z * w4.z; wsq[rep].w = w4.w * w4.w;
            l[rep] = wsq[rep].x * iv[rep].x + wsq[rep].y * iv[rep].y
                   + wsq[rep].z * iv[rep].z + wsq[rep].w * iv[rep].w;
        }
        #pragma unroll
        for (int off = 1; off < 16; off <<= 1)
            #pragma unroll
            for (int rep = 0; rep < 4; ++rep) l[rep] += __shfl_xor(l[rep], off, 64);
        #pragma unroll
        for (int rep = 0; rep < 4; ++rep) l[rep] *= tl[rep];

        float m = fmaxf(fmaxf(l[0], l[1]), fmaxf(l[2], l[3]));
        m = fmaxf(m, __shfl_xor(m, 16, 64));
        m = fmaxf(m, __shfl_xor(m, 32, 64));
        float e[4], s = 0.f;
        #pragma unroll
        for (int rep = 0; rep < 4; ++rep) { e[rep] = expf(l[rep] - m); s += e[rep]; }
        s += __shfl_xor(s, 16, 64);
        s += __shfl_xor(s, 32, 64);
        const float inv_s = 1.0f / s;

        float pi[4];
        #pragma unroll
        for (int rep = 0; rep < 4; ++rep) pi[rep] = e[rep] * inv_s;

        #pragma unroll
        for (int rep = 0; rep < 4; ++rep) {
            const int c = rep * 256 + lane * 4;
            float4* t = (float4*)&Tacc[wv][c];
            float4 tv = *t;
            tv.x = fmaf(pi[rep], wsq[rep].x, tv.x);
            tv.y = fmaf(pi[rep], wsq[rep].y, tv.y);
            tv.z = fmaf(pi[rep], wsq[rep].z, tv.z);
            tv.w = fmaf(pi[rep], wsq[rep].w, tv.w);
            *t = tv;
        }

        if ((lane & 15) == 0) {
            #pragma unroll
            for (int rep = 0; rep < 4; ++rep) {
                Pi[(size_t)r * H_ + rep * 4 + g] = pi[rep];
                sSl[rep] += pi[rep];
            }
        }
    }

    if ((lane & 15) == 0) {
        #pragma unroll
        for (int rep = 0; rep < 4; ++rep) atomicAdd(&sS[rep * 4 + g], sSl[rep]);
    }
    __syncthreads();
    if (tid < H_) atomicAdd(&S[b * H_ + tid], sS[tid]);
    #pragma unroll
    for (int z = 0; z < 4; ++z) {
        const int c = z * 256 + tid;
        const float t = Tacc[0][c] + Tacc[1][c] + Tacc[2][c] + Tacc[3][c];
        atomicAdd(&T[b * DIM_ + c], t);
    }
}

// ============================================================================
// a2h = bf16( -w * Pi[r, c/64] * attn(b,c) ),  attn = 1/(1 + T/(S+eps)).
// 8 elements/thread (16B stores); 8 consecutive cols stay in one head.
// ============================================================================
__global__ __launch_bounds__(256)
void split_scaled(const float* __restrict__ w, const float* __restrict__ Pi,
                  const float* __restrict__ S, const float* __restrict__ T,
                  u16* __restrict__ ah)
{
    const int i = blockIdx.x * 256 + threadIdx.x;   // over M_*DIM_/8
    const int r = i >> 7;
    const int c = (i & 127) * 8;                    // 8 cols, same head
    const int b = r >> 12;
    const int h = c >> 6;
    const float p  = -Pi[(size_t)r * H_ + h];
    const float Sv = S[b * H_ + h] + 1e-8f;
    const float4 T0 = *(const float4*)(T + b * DIM_ + c);
    const float4 T1 = *(const float4*)(T + b * DIM_ + c + 4);
    const float4 w0 = ((const float4*)w)[i * 2];
    const float4 w1 = ((const float4*)w)[i * 2 + 1];
    ushort8 oh;
    oh[0] = f2bf(w0.x * p / (1.0f + T0.x / Sv));
    oh[1] = f2bf(w0.y * p / (1.0f + T0.y / Sv));
    oh[2] = f2bf(w0.z * p / (1.0f + T0.z / Sv));
    oh[3] = f2bf(w0.w * p / (1.0f + T0.w / Sv));
    oh[4] = f2bf(w1.x * p / (1.0f + T1.x / Sv));
    oh[5] = f2bf(w1.y * p / (1.0f + T1.y / Sv));
    oh[6] = f2bf(w1.z * p / (1.0f + T1.z / Sv));
    oh[7] = f2bf(w1.w * p / (1.0f + T1.w / Sv));
    ((ushort8*)ah)[i] = oh;
}

// ============================================================================
// ===================== fp32 VALU fallback path (round-0) ====================
// ============================================================================
template<bool FUSE>
__global__ __launch_bounds__(256, 4)
void gemm128(const float* __restrict__ A, const float* __restrict__ Bw,
             const float* __restrict__ bias, float* __restrict__ C,
             const float* __restrict__ Pi, const float* __restrict__ attn)
{
    __shared__ float As[16][128];
    __shared__ float Bs[16][128];
    const int tid  = threadIdx.x;
    const int bx   = blockIdx.x;
    const int by   = blockIdx.y;
    const int lrow = tid >> 2;
    const int lk   = (tid & 3) << 2;
    const int tx   = tid & 15;
    const int ty   = tid >> 4;
    const size_t K = DIM_;
    const float* Ap = A  + (size_t)(by * 128 + lrow) * K + lk;
    const float* Bp = Bw + (size_t)(bx * 128 + lrow) * K + lk;

    float acc[8][8];
    #pragma unroll
    for (int i = 0; i < 8; ++i)
        #pragma unroll
        for (int j = 0; j < 8; ++j) acc[i][j] = 0.f;

    for (int k0 = 0; k0 < DIM_; k0 += 16) {
        float4 a0 = *(const float4*)(Ap + k0);
        float4 a1 = *(const float4*)(Ap + k0 + (size_t)64 * K);
        float4 b0 = *(const float4*)(Bp + k0);
        float4 b1 = *(const float4*)(Bp + k0 + (size_t)64 * K);
        if (FUSE) {
            const int r0 = by * 128 + lrow;
            const int c  = k0 + lk;
            const int b  = r0 >> 12;
            const float4 at = *(const float4*)(attn + b * DIM_ + c);
            const float p0 = -Pi[(size_t)r0 * H_ + (c >> 6)];
            const float p1 = -Pi[(size_t)(r0 + 64) * H_ + (c >> 6)];
            a0.x *= p0 * at.x; a0.y *= p0 * at.y; a0.z *= p0 * at.z; a0.w *= p0 * at.w;
            a1.x *= p1 * at.x; a1.y *= p1 * at.y; a1.z *= p1 * at.z; a1.w *= p1 * at.w;
        }
        __syncthreads();
        As[lk + 0][lrow]      = a0.x; As[lk + 1][lrow]      = a0.y;
        As[lk + 2][lrow]      = a0.z; As[lk + 3][lrow]      = a0.w;
        As[lk + 0][lrow + 64] = a1.x; As[lk + 1][lrow + 64] = a1.y;
        As[lk + 2][lrow + 64] = a1.z; As[lk + 3][lrow + 64] = a1.w;
        Bs[lk + 0][lrow]      = b0.x; Bs[lk + 1][lrow]      = b0.y;
        Bs[lk + 2][lrow]      = b0.z; Bs[lk + 3][lrow]      = b0.w;
        Bs[lk + 0][lrow + 64] = b1.x; Bs[lk + 1][lrow + 64] = b1.y;
        Bs[lk + 2][lrow + 64] = b1.z; Bs[lk + 3][lrow + 64] = b1.w;
        __syncthreads();
        #pragma unroll
        for (int kk = 0; kk < 16; ++kk) {
            const float4 av0 = *(const float4*)&As[kk][ty * 4];
            const float4 av1 = *(const float4*)&As[kk][ty * 4 + 64];
            const float4 bv0 = *(const float4*)&Bs[kk][tx * 4];
            const float4 bv1 = *(const float4*)&Bs[kk][tx * 4 + 64];
            const float a[8] = {av0.x, av0.y, av0.z, av0.w, av1.x, av1.y, av1.z, av1.w};
            const float b[8] = {bv0.x, bv0.y, bv0.z, bv0.w, bv1.x, bv1.y, bv1.z, bv1.w};
            #pragma unroll
            for (int i = 0; i < 8; ++i)
                #pragma unroll
                for (int j = 0; j < 8; ++j)
                    acc[i][j] = fmaf(a[i], b[j], acc[i][j]);
        }
    }
    #pragma unroll
    for (int i = 0; i < 8; ++i) {
        const int r = by * 128 + ((i < 4) ? (ty * 4 + i) : (64 + ty * 4 + (i - 4)));
        #pragma unroll
        for (int jb = 0; jb < 2; ++jb) {
            const int c0 = bx * 128 + (jb ? (64 + tx * 4) : (tx * 4));
            float4 v;
            v.x = acc[i][jb * 4 + 0]; v.y = acc[i][jb * 4 + 1];
            v.z = acc[i][jb * 4 + 2]; v.w = acc[i][jb * 4 + 3];
            if (bias) {
                const float4 bv = *(const float4*)(bias + c0);
                v.x += bv.x; v.y += bv.y; v.z += bv.z; v.w += bv.w;
            }
            *(float4*)(C + (size_t)r * DIM_ + c0) = v;
        }
    }
}

__global__ __launch_bounds__(256)
void colsum_sq_f32(const float* __restrict__ w, float* __restrict__ norm2)
{
    const int c  = blockIdx.x * 256 + threadIdx.x;
    const int b  = blockIdx.z;
    const int n0 = blockIdx.y * (N_ / 16);
    const float* p = w + (size_t)(b * N_ + n0) * DIM_ + c;
    float s = 0.f;
    for (int n = 0; n < N_ / 16; ++n) {
        const float v = p[(size_t)n * DIM_];
        s = fmaf(v, v, s);
    }
    atomicAdd(&norm2[b * DIM_ + c], s);
}

__global__ void finalize_inv(float* __restrict__ norm2)
{
    const int i = blockIdx.x * 256 + threadIdx.x;   // 8192
    norm2[i] = 1.0f / fmaxf(norm2[i], 1e-24f);
}

__global__ __launch_bounds__(256)
void softmax_heads_f32(const float* __restrict__ w, const float* __restrict__ inv2,
                       const float* __restrict__ temp, float* __restrict__ Pi,
                       float* __restrict__ S)
{
    __shared__ float sS[H_];
    const int tid = threadIdx.x;
    if (tid < H_) sS[tid] = 0.f;
    __syncthreads();
    const int wv   = tid >> 6;
    const int lane = tid & 63;
    const int r    = blockIdx.x * 4 + wv;
    const int b    = r >> 12;
    const int g    = lane >> 4;
    float l[4];
    #pragma unroll
    for (int rep = 0; rep < 4; ++rep) {
        const int c = rep * 256 + lane * 4;
        const float4 wv4 = *(const float4*)(w    + (size_t)r * DIM_ + c);
        const float4 iv4 = *(const float4*)(inv2 + (size_t)b * DIM_ + c);
        l[rep] = wv4.x * wv4.x * iv4.x + wv4.y * wv4.y * iv4.y
               + wv4.z * wv4.z * iv4.z + wv4.w * wv4.w * iv4.w;
    }
    #pragma unroll
    for (int off = 1; off < 16; off <<= 1)
        #pragma unroll
        for (int rep = 0; rep < 4; ++rep) l[rep] += __shfl_xor(l[rep], off, 64);
    #pragma unroll
    for (int rep = 0; rep < 4; ++rep) l[rep] *= temp[rep * 4 + g];
    float m = fmaxf(fmaxf(l[0], l[1]), fmaxf(l[2], l[3]));
    m = fmaxf(m, __shfl_xor(m, 16, 64));
    m = fmaxf(m, __shfl_xor(m, 32, 64));
    float e[4], s = 0.f;
    #pragma unroll
    for (int rep = 0; rep < 4; ++rep) { e[rep] = expf(l[rep] - m); s += e[rep]; }
    s += __shfl_xor(s, 16, 64);
    s += __shfl_xor(s, 32, 64);
    const float inv_s = 1.0f / s;
    if ((lane & 15) == 0) {
        #pragma unroll
        for (int rep = 0; rep < 4; ++rep) {
            const float pi = e[rep] * inv_s;
            Pi[(size_t)r * H_ + rep * 4 + g] = pi;
            atomicAdd(&sS[rep * 4 + g], pi);
        }
    }
    __syncthreads();
    if (tid < H_) atomicAdd(&S[b * H_ + tid], sS[tid]);
}

__global__ __launch_bounds__(256)
void colsum_T_f32(const float* __restrict__ w, const float* __restrict__ Pi,
                  float* __restrict__ T)
{
    const int c  = blockIdx.x * 256 + threadIdx.x;
    const int b  = blockIdx.z;
    const int n0 = blockIdx.y * (N_ / 16);
    const int h  = c >> 6;
    const float* p  = w  + (size_t)(b * N_ + n0) * DIM_ + c;
    const float* pp = Pi + (size_t)(b * N_ + n0) * H_ + h;
    float s = 0.f;
    for (int n = 0; n < N_ / 16; ++n) {
        const float v = p[(size_t)n * DIM_];
        s = fmaf(pp[(size_t)n * H_] * v, v, s);
    }
    atomicAdd(&T[b * DIM_ + c], s);
}

__global__ void finalize_attn(const float* __restrict__ T, const float* __restrict__ S,
                              float* __restrict__ attn)
{
    const int i = blockIdx.x * 256 + threadIdx.x;   // 8192
    const int b = i >> 10;
    const int c = i & 1023;
    const float dots = T[i] / (S[b * H_ + (c >> 6)] + 1e-8f);
    attn[i] = 1.0f / (1.0f + dots);
}

// ============================================================================
extern "C" void kernel_launch(void* const* d_in, const int* in_sizes, int n_in,
                              void* d_out, int out_size, void* d_ws, size_t ws_size,
                              hipStream_t stream)
{
    const float* x    = (const float*)d_in[0];
    const float* Wqkv = (const float*)d_in[1];
    const float* temp = (const float*)d_in[2];
    const float* Wout = (const float*)d_in[3];
    const float* bout = (const float*)d_in[4];
    float* out = (float*)d_out;

    const size_t MD = (size_t)M_ * DIM_;          // 33,554,432
    const size_t DD = (size_t)DIM_ * DIM_;        // 1,048,576
    const size_t NEED_MFMA = MD * 2            // xh (reused as a2h)
                           + MD * 4            // w fp32
                           + 4 * DD * 2        // qh, ql, oh, ol
                           + (size_t)M_ * H_ * 4
                           + (size_t)(8192 + 128 + 8192) * 4 + 4096;

    if (ws_size >= NEED_MFMA) {
        // ---------------- 2-term split-bf16 MFMA path (r5-proven) ----------
        uint8_t* p = (uint8_t*)d_ws;
        u16* xh = (u16*)p; p += MD * 2;   // reused as a2h
        float* w = (float*)p; p += MD * 4;
        u16* qh = (u16*)p; p += DD * 2;
        u16* ql = (u16*)p; p += DD * 2;
        u16* oh = (u16*)p; p += DD * 2;
        u16* ol = (u16*)p; p += DD * 2;
        float* Pi    = (float*)p; p += (size_t)M_ * H_ * 4;
        float* norm2 = (float*)p; p += 8192 * 4;
        float* S     = (float*)p; p += 128 * 4;
        float* T     = (float*)p;

        // 0) weight splits + stats zeroing (norm2,S,T contiguous)
        prep<<<1024, 256, 0, stream>>>(Wqkv, Wout, qh, ql, oh, ol, norm2);
        // 0b) x -> bf16
        cvt_bf16<<<(int)(MD / 8 / 256), 256, 0, stream>>>(x, xh, (int)(MD / 8));

        // 1) w = x @ Wqkv^T (fp32 out) + fused norm2 = col sum of w^2
        gemm_mfma<1><<<1024, 512, 0, stream>>>(xh, qh, ql, nullptr, w, norm2);

        // 2) fused softmax(Pi) + S + T (inv2 inline from norm2)
        softmax_T<<<M_ / 64, 256, 0, stream>>>(w, norm2, temp, Pi, S, T);

        // 3) a2h = bf16(-(w*Pi)*attn), attn inline from T,S
        split_scaled<<<(int)(MD / 8 / 256), 256, 0, stream>>>(w, Pi, S, T, xh);

        // 4) out = a2 @ Wout^T + bout
        gemm_mfma<0><<<1024, 512, 0, stream>>>(xh, oh, ol, bout, out, nullptr);
    } else {
        // ---------------- fp32 VALU fallback ----------------
        float* ws    = (float*)d_ws;
        float* w     = ws;
        float* Pi    = w + MD;
        float* norm2 = Pi + (size_t)M_ * H_;
        float* S     = norm2 + 8192;
        float* T     = S + 128;
        float* attnv = T + 8192;

        hipMemsetAsync(norm2, 0, (size_t)(8192 + 128 + 8192) * 4, stream);

        gemm128<false><<<dim3(8, 256), 256, 0, stream>>>(x, Wqkv, nullptr, w, nullptr, nullptr);
        colsum_sq_f32<<<dim3(4, 16, 8), 256, 0, stream>>>(w, norm2);
        finalize_inv<<<32, 256, 0, stream>>>(norm2);
        softmax_heads_f32<<<M_ / 4, 256, 0, stream>>>(w, norm2, temp, Pi, S);
        colsum_T_f32<<<dim3(4, 16, 8), 256, 0, stream>>>(w, Pi, T);
        finalize_attn<<<32, 256, 0, stream>>>(T, S, attnv);
        gemm128<true><<<dim3(8, 256), 256, 0, stream>>>(w, Wout, bout, out, Pi, attnv);
    }
}